// Round 1
// 852.763 us; speedup vs baseline: 1.0146x; 1.0146x over previous
//
#include <hip/hip_runtime.h>
#include <stdint.h>

#define NT 256        // threads per block
#define NV 16         // 16B vectors per thread -> 64 elements/thread
#define PART 16384    // elements per partition
#define KSEL 32u      // top-k
#define CAP 2048      // candidate-list capacity (fallback beyond this)

// Native clang vector type: __builtin_nontemporal_* accepts these (HIP's uint4
// class type is rejected).
typedef uint32_t u32x4 __attribute__((ext_vector_type(4)));

// Order-preserving float->uint transform: larger float <=> larger uint.
__device__ __forceinline__ uint32_t xform(uint32_t u) {
    return (u & 0x80000000u) ? ~u : (u | 0x80000000u);
}

__global__ __launch_bounds__(NT, 4) void topk_scatter_kernel(
        const uint32_t* __restrict__ x, uint32_t* __restrict__ out) {
    // 16B-aligned so the rank scan can use ds_read_b128 broadcasts.
    __shared__ __align__(16) uint32_t maxima[NT];   // per-thread maxima
    __shared__ uint32_t cand_key[CAP];   // candidate keys (>= pivot)
    __shared__ uint16_t cand_idx[CAP];   // candidate indices within partition
    __shared__ uint32_t red[8];          // cross-wave reduction scratch
    __shared__ uint32_t sh_P, sh_cnt, sh_T, sh_gt, sh_eq;

    const size_t base = (size_t)blockIdx.x * (size_t)PART;
    const u32x4* __restrict__ xin = (const u32x4*)(x + base);
    u32x4* __restrict__ xout = (u32x4*)(out + base);
    const int t = threadIdx.x;

    // ---- Load 64 elements/thread into registers (coalesced, streaming) ----
    u32x4 k[NV];
#pragma unroll
    for (int i = 0; i < NV; ++i) k[i] = __builtin_nontemporal_load(&xin[t + NT * i]);

    // ---- Transform to order-preserving keys; track per-thread max ----
    uint32_t mymax = 0;
#pragma unroll
    for (int i = 0; i < NV; ++i) {
#pragma unroll
        for (int c = 0; c < 4; ++c) {
            k[i][c] = xform(k[i][c]);
            mymax = max(mymax, k[i][c]);
        }
    }

    if (t == 0) { sh_P = 0xFFFFFFFFu; sh_cnt = 0; sh_T = 0xFFFFFFFFu; sh_gt = 0; sh_eq = 0; }
    maxima[t] = mymax;
    __syncthreads();

    // ---- Pivot P = exact 32nd-largest of the 256 per-thread maxima.
    // Vectorized scan: u32x4 broadcast LDS reads (ds_read_b128, all lanes same
    // address -> conflict-free), 64 iterations instead of 256.
    uint32_t cgt = 0;
    const u32x4* __restrict__ mv = (const u32x4*)maxima;
#pragma unroll 8
    for (int j = 0; j < NT / 4; ++j) {
        const u32x4 mm = mv[j];
        cgt += (mm[0] > mymax) ? 1u : 0u;
        cgt += (mm[1] > mymax) ? 1u : 0u;
        cgt += (mm[2] > mymax) ? 1u : 0u;
        cgt += (mm[3] > mymax) ? 1u : 0u;
    }
    if (cgt < KSEL) atomicMin(&sh_P, mymax);  // P = min of top-32 maxima
    __syncthreads();
    const uint32_t P = sh_P;
    // Guarantee: >=32 threads have max >= P, each contributes >=1 element >= P,
    // so count(elements >= P) >= 32 and therefore T (32nd largest) >= P.

    // ---- Gather candidates (key >= P) into LDS; expected ~30-60 for N(0,1) ----
#pragma unroll
    for (int i = 0; i < NV; ++i) {
        const uint32_t e0 = 4u * (uint32_t)(t + NT * i);
#pragma unroll
        for (int c = 0; c < 4; ++c) {
            const uint32_t u = k[i][c];
            if (u >= P) {
                uint32_t p = atomicAdd(&sh_cnt, 1u);
                if (p < CAP) { cand_key[p] = u; cand_idx[p] = (uint16_t)(e0 + (uint32_t)c); }
            }
        }
    }
    __syncthreads();
    uint32_t m = sh_cnt;

    uint32_t T, r;
    bool need_order;

    if (m <= CAP) {
        // ---- Exact select among candidates: T = min{key : count(keys > key) < 32} ----
        for (uint32_t j = t; j < m; j += NT) {
            const uint32_t kj = cand_key[j];
            uint32_t c = 0;
            for (uint32_t i2 = 0; i2 < m; ++i2) c += (cand_key[i2] > kj) ? 1u : 0u;
            if (c < KSEL) atomicMin(&sh_T, kj);
        }
        __syncthreads();
        T = sh_T;
        // Fused gt/eq: only the thread(s) owning a candidate equal to T recount.
        // All such writers produce identical values -> benign same-value race.
        for (uint32_t j = t; j < m; j += NT) {
            if (cand_key[j] == T) {
                uint32_t g = 0, e = 0;
                for (uint32_t i2 = 0; i2 < m; ++i2) {
                    const uint32_t kk = cand_key[i2];
                    g += (kk > T) ? 1u : 0u;
                    e += (kk == T) ? 1u : 0u;
                }
                sh_gt = g; sh_eq = e;
                break;
            }
        }
        __syncthreads();
        r = KSEL - sh_gt;               // ties to include
        need_order = (sh_eq != r);      // boundary tie needing index order
        // cand list already holds every element == T (all are >= P)
    } else {
        // ---- Cold fallback: 32-round bitwise search (exact, contention-free) ----
        uint32_t pref = 0;
        for (int b = 31; b >= 0; --b) {
            const uint32_t trial = pref | (1u << b);
            uint32_t lc = 0;
#pragma unroll
            for (int i = 0; i < NV; ++i) {
#pragma unroll
                for (int c = 0; c < 4; ++c) lc += (k[i][c] >= trial) ? 1u : 0u;
            }
#pragma unroll
            for (int off = 32; off; off >>= 1) lc += __shfl_down(lc, off);
            if ((t & 63) == 0) red[t >> 6] = lc;
            __syncthreads();
            if (t == 0) sh_gt = red[0] + red[1] + red[2] + red[3];
            __syncthreads();
            if (sh_gt >= KSEL) pref = trial;
            // next iteration's red[] writes are ordered by its own __syncthreads
        }
        T = pref;
        // count > T and == T over registers
        uint32_t lgt = 0, leq = 0;
#pragma unroll
        for (int i = 0; i < NV; ++i) {
#pragma unroll
            for (int c = 0; c < 4; ++c) {
                lgt += (k[i][c] > T) ? 1u : 0u;
                leq += (k[i][c] == T) ? 1u : 0u;
            }
        }
#pragma unroll
        for (int off = 32; off; off >>= 1) { lgt += __shfl_down(lgt, off); leq += __shfl_down(leq, off); }
        if ((t & 63) == 0) { red[t >> 6] = lgt; red[4 + (t >> 6)] = leq; }
        __syncthreads();
        if (t == 0) {
            sh_gt = red[0] + red[1] + red[2] + red[3];
            sh_eq = red[4] + red[5] + red[6] + red[7];
        }
        __syncthreads();
        r = KSEL - sh_gt;
        need_order = (sh_eq != r);
        if (need_order) {
            if (t == 0) sh_cnt = 0;
            __syncthreads();
#pragma unroll
            for (int i = 0; i < NV; ++i) {
                const uint32_t e0 = 4u * (uint32_t)(t + NT * i);
#pragma unroll
                for (int c = 0; c < 4; ++c) {
                    if (k[i][c] == T) {
                        uint32_t p = atomicAdd(&sh_cnt, 1u);
                        if (p < CAP) { cand_key[p] = T; cand_idx[p] = (uint16_t)(e0 + (uint32_t)c); }
                    }
                }
            }
            __syncthreads();
            m = sh_cnt < CAP ? sh_cnt : CAP;
        } else {
            m = 0;
        }
    }

    // ---- Write pass: coalesced streaming 16B stores ----
#pragma unroll
    for (int i = 0; i < NV; ++i) {
        const uint32_t e0 = 4u * (uint32_t)(t + NT * i);
        u32x4 o;
#pragma unroll
        for (int c = 0; c < 4; ++c) {
            const uint32_t u = k[i][c];
            bool sel;
            if (u > T) {
                sel = true;
            } else if (u == T) {
                if (!need_order) {
                    sel = true;
                } else {
                    const uint32_t eidx = e0 + (uint32_t)c;
                    uint32_t rank = 0;
                    for (uint32_t j = 0; j < m; ++j)
                        rank += (cand_key[j] == T && (uint32_t)cand_idx[j] < eidx) ? 1u : 0u;
                    sel = (rank < r);   // keep the r lowest-indexed ties
                }
            } else {
                sel = false;
            }
            // relu: original float >= 0 iff key >= 0x80000000; bits = key ^ 0x80000000.
            o[c] = (sel && (u & 0x80000000u)) ? (u ^ 0x80000000u) : 0u;
        }
        __builtin_nontemporal_store(o, &xout[t + NT * i]);
    }
}

extern "C" void kernel_launch(void* const* d_in, const int* in_sizes, int n_in,
                              void* d_out, int out_size, void* d_ws, size_t ws_size,
                              hipStream_t stream) {
    const uint32_t* x = (const uint32_t*)d_in[0];
    uint32_t* out = (uint32_t*)d_out;
    const int nparts = in_sizes[0] / PART;  // 4096 rows * 2 partitions = 8192
    topk_scatter_kernel<<<dim3(nparts), dim3(NT), 0, stream>>>(x, out);
}